// Round 7
// baseline (273.247 us; speedup 1.0000x reference)
//
#include <hip/hip_runtime.h>
#include <hip/hip_bf16.h>
#include <cstdint>
#include <cstddef>

// Problem constants: T=1024, H=1024, I=512, E=16, K=4
#define T_TOK 1024
#define HDIM  1024
#define IDIM  512
#define NEXP  16
#define TOPK  4
#define CAP   1024   // per-expert entry capacity
#define MAXTILES 48  // max sum of ceil(cnt_e/128) = 4096/128 + 16 = 48

typedef __bf16 bf16;
typedef __attribute__((ext_vector_type(8))) __bf16 bf16x8;
typedef __attribute__((ext_vector_type(4))) __bf16 bf16x4;
typedef __attribute__((ext_vector_type(4))) float f32x4;

__device__ __forceinline__ bf16x4 cvt4(float4 a) {
  bf16x4 o;
  o[0] = (bf16)a.x; o[1] = (bf16)a.y; o[2] = (bf16)a.z; o[3] = (bf16)a.w;
  return o;
}

__device__ __forceinline__ bf16x8 pack8(float4 a, float4 b) {
  bf16x8 o;
  o[0] = (bf16)a.x; o[1] = (bf16)a.y; o[2] = (bf16)a.z; o[3] = (bf16)a.w;
  o[4] = (bf16)b.x; o[5] = (bf16)b.y; o[6] = (bf16)b.z; o[7] = (bf16)b.w;
  return o;
}

// flat tile index -> (expert, m-tile) by scanning cntpad. false => idle block.
__device__ __forceinline__ bool tile_lookup(const int* cntpad, int idx,
                                            int& e_out, int& mt_out) {
  int rem = idx;
  for (int e = 0; e < NEXP; ++e) {
    int nt = cntpad[e] >> 7;
    if (rem < nt) { e_out = e; mt_out = rem; return true; }
    rem -= nt;
  }
  return false;
}

// ---------------- fused prep: cvt hid->bf16, zero out, routing ----------------

#define CVT_BLOCKS (T_TOK * HDIM / 4 / 256)   // 1024

__global__ void prep_kernel(const float* __restrict__ hid_f, bf16* __restrict__ hid_b,
                            const int* __restrict__ idx, const float* __restrict__ w,
                            int* __restrict__ etk, float* __restrict__ ew,
                            int* __restrict__ cntpad, float* __restrict__ out) {
  __shared__ int cnt;
  const int b = blockIdx.x;
  const int tid = threadIdx.x;
  if (b < CVT_BLOCKS) {
    int i = b * 256 + tid;
    float4 v = ((const float4*)hid_f)[i];
    ((bf16x4*)hid_b)[i] = cvt4(v);
    ((float4*)out)[i] = make_float4(0.f, 0.f, 0.f, 0.f);
    if (b == 0)  // zero pad row T
      ((bf16x4*)(hid_b + (size_t)T_TOK * HDIM))[tid] = cvt4(make_float4(0.f, 0.f, 0.f, 0.f));
    return;
  }
  const int e = b - CVT_BLOCKS;
  if (tid == 0) cnt = 0;
  __syncthreads();
  for (int j = tid; j < T_TOK * TOPK; j += blockDim.x) {
    if (idx[j] == e) {
      int slot = atomicAdd(&cnt, 1);
      if (slot < CAP) { etk[e * CAP + slot] = j; ew[e * CAP + slot] = w[j]; }
    }
  }
  __syncthreads();
  int c = cnt < CAP ? cnt : CAP;
  int p = (c + 127) & ~127;            // pad to M-tile (128)
  for (int j = c + tid; j < p; j += blockDim.x) {
    etk[e * CAP + j] = (T_TOK << 2);   // points at zeroed row T
    ew[e * CAP + j] = 0.f;
  }
  if (tid == 0) cntpad[e] = p;
}

// ---------------- GEMM1: hsc[entry, i] = silu(g)*u*wgt ----------------
// v7: PURE-REGISTER dataflow. No LDS, no barriers, no inline asm. Each wave
// loads its own A fragments (bf16x8, m89-verified layout: row=lcol, k=lquad*8)
// and B fragments (fp32 -> pack8 in-reg) directly from global, pipelined one
// K-step ahead with fully static register sets (manual 2-step unroll).
// Compiler emits exact counted vmcnt per dependency; zero cross-wave coupling
// -> every wave keeps ~16 loads in flight continuously.
// Tile M=128 x 32 i-ch (G+U); waves 2m x 2i (wave-tile 64x16); BK=64, 16 steps,
// 16 MFMA/wave/step. One (e,mt) tile per block (cntpad scan). Grid (16,48).

__global__ __launch_bounds__(256, 2) void gemm1_kernel(
    const bf16* __restrict__ hid,    // [(T+1),H] bf16, row T zeroed
    const float* __restrict__ gup,   // [E,2I,H] fp32
    const int* __restrict__ etk, const float* __restrict__ ew,
    const int* __restrict__ cntpad,
    bf16* __restrict__ hsc) {        // [E*CAP, I] bf16
  int e, mt;
  if (!tile_lookup(cntpad, blockIdx.y, e, mt)) return;
  const int n0 = blockIdx.x * 32;
  const int ebase = e * CAP;
  const int tid = threadIdx.x, lane = tid & 63, wid = tid >> 6;
  const int wm = (wid >> 1) * 64, wi = (wid & 1) * 16;
  const int lcol = lane & 15, lquad = lane >> 4;

  // per-lane A row pointers (gathered tokens), pre-offset by lquad*8 k-slice
  const bf16* pA[4];
#pragma unroll
  for (int mf = 0; mf < 4; ++mf) {
    const int trow = etk[ebase + mt * 128 + wm + mf * 16 + lcol] >> 2;
    pA[mf] = hid + (size_t)trow * HDIM + lquad * 8;
  }
  // B row = i-channel (n0+wi+lcol); G and U streams
  const float* pG = gup + (size_t)e * (2 * IDIM) * HDIM
                  + (size_t)(n0 + wi + lcol) * HDIM + lquad * 8;
  const float* pU = pG + (size_t)IDIM * HDIM;

  f32x4 aG[4], aU[4];
#pragma unroll
  for (int mf = 0; mf < 4; ++mf) {
    aG[mf] = f32x4{0.f, 0.f, 0.f, 0.f};
    aU[mf] = f32x4{0.f, 0.f, 0.f, 0.f};
  }

  // fragment loaders: step k covers orig-k [k*64, k*64+64); frag (mf,ks) at
  // pA[mf] + k*64 + ks*32 (bf16); B (ks,j) at pG/pU + k*64 + ks*32 + j*4 (fp32)
  auto LDA = [&](int k, bf16x8 (&a)[8]) {
#pragma unroll
    for (int mf = 0; mf < 4; ++mf)
#pragma unroll
      for (int ks = 0; ks < 2; ++ks)
        a[mf * 2 + ks] = *(const bf16x8*)(pA[mf] + k * 64 + ks * 32);
  };
  auto LDB = [&](int k, float4 (&g)[4], float4 (&u)[4]) {
#pragma unroll
    for (int ks = 0; ks < 2; ++ks)
#pragma unroll
      for (int j = 0; j < 2; ++j) {
        g[ks * 2 + j] = *(const float4*)(pG + k * 64 + ks * 32 + j * 4);
        u[ks * 2 + j] = *(const float4*)(pU + k * 64 + ks * 32 + j * 4);
      }
  };
  auto COMP = [&](bf16x8 (&a)[8], float4 (&g)[4], float4 (&u)[4]) {
#pragma unroll
    for (int ks = 0; ks < 2; ++ks) {
      bf16x8 bg = pack8(g[ks * 2], g[ks * 2 + 1]);
      bf16x8 bu = pack8(u[ks * 2], u[ks * 2 + 1]);
#pragma unroll
      for (int mf = 0; mf < 4; ++mf) {
        aG[mf] = __builtin_amdgcn_mfma_f32_16x16x32_bf16(a[mf * 2 + ks], bg, aG[mf], 0, 0, 0);
        aU[mf] = __builtin_amdgcn_mfma_f32_16x16x32_bf16(a[mf * 2 + ks], bu, aU[mf], 0, 0, 0);
      }
    }
  };

  bf16x8 a0[8], a1[8];
  float4 g0[4], u0[4], g1[4], u1[4];
  LDA(0, a0); LDB(0, g0, u0);
#pragma unroll
  for (int kk = 0; kk < 8; ++kk) {
    const int k = 2 * kk;
    if (k + 1 < 16) { LDA(k + 1, a1); LDB(k + 1, g1, u1); }
    COMP(a0, g0, u0);
    if (k + 2 < 16) { LDA(k + 2, a0); LDB(k + 2, g0, u0); }
    COMP(a1, g1, u1);
  }

  // epilogue: C/D col=lane&15, row=lquad*4+rr
#pragma unroll
  for (int mf = 0; mf < 4; ++mf) {
#pragma unroll
    for (int rr = 0; rr < 4; ++rr) {
      const int erow = mt * 128 + wm + mf * 16 + lquad * 4 + rr;
      const float wgt = ew[ebase + erow];
      float g = aG[mf][rr], u = aU[mf][rr];
      float s = g / (1.f + __expf(-g));
      hsc[(size_t)(ebase + erow) * IDIM + n0 + wi + lcol] = (bf16)(s * u * wgt);
    }
  }
}

// ---------------- GEMM2: out[tok,h] += hsc[entry,:] . down[e,h,:] ----------------
// Same pure-register dataflow. Tile M=128 x 32 h-ch; waves 2m x 2h (64x16);
// BK=32, 16 steps, 4 MFMA/wave/step. A rows contiguous (hsc entries).
// Grid (32,48) ~= 1024 active blocks -> 4 blocks/CU = 16 waves/CU
// (launch_bounds(256,4), ~100 VGPR). atomicAdd epilogue into pre-zeroed out.

__global__ __launch_bounds__(256, 4) void gemm2_kernel(
    const bf16* __restrict__ hsc,    // [E*CAP, I] bf16
    const float* __restrict__ down,  // [E,H,I] fp32
    const int* __restrict__ etk, const int* __restrict__ cntpad,
    float* __restrict__ out) {       // [T,H] fp32, pre-zeroed
  int e, mt;
  if (!tile_lookup(cntpad, blockIdx.y, e, mt)) return;
  const int n0 = blockIdx.x * 32;
  const int ebase = e * CAP;
  const int tid = threadIdx.x, lane = tid & 63, wid = tid >> 6;
  const int wm = (wid >> 1) * 64, wh = (wid & 1) * 16;
  const int lcol = lane & 15, lquad = lane >> 4;

  const bf16* pA[4];
#pragma unroll
  for (int mf = 0; mf < 4; ++mf)
    pA[mf] = hsc + (size_t)(ebase + mt * 128 + wm + mf * 16 + lcol) * IDIM + lquad * 8;
  const float* pB = down + (size_t)e * HDIM * IDIM
                  + (size_t)(n0 + wh + lcol) * IDIM + lquad * 8;

  f32x4 acc[4];
#pragma unroll
  for (int mf = 0; mf < 4; ++mf) acc[mf] = f32x4{0.f, 0.f, 0.f, 0.f};

  auto LDA = [&](int k, bf16x8 (&a)[4]) {
#pragma unroll
    for (int mf = 0; mf < 4; ++mf)
      a[mf] = *(const bf16x8*)(pA[mf] + k * 32);
  };
  auto LDB = [&](int k, float4 (&b)[2]) {
#pragma unroll
    for (int j = 0; j < 2; ++j)
      b[j] = *(const float4*)(pB + k * 32 + j * 4);
  };
  auto COMP = [&](bf16x8 (&a)[4], float4 (&b)[2]) {
    bf16x8 bv = pack8(b[0], b[1]);
#pragma unroll
    for (int mf = 0; mf < 4; ++mf)
      acc[mf] = __builtin_amdgcn_mfma_f32_16x16x32_bf16(a[mf], bv, acc[mf], 0, 0, 0);
  };

  bf16x8 a0[4], a1[4];
  float4 b0[2], b1[2];
  LDA(0, a0); LDB(0, b0);
#pragma unroll
  for (int kk = 0; kk < 8; ++kk) {   // 16 steps of BK=32 (IDIM=512)
    const int k = 2 * kk;
    if (k + 1 < 16) { LDA(k + 1, a1); LDB(k + 1, b1); }
    COMP(a0, b0);
    if (k + 2 < 16) { LDA(k + 2, a0); LDB(k + 2, b0); }
    COMP(a1, b1);
  }

  // epilogue: atomic scatter-accumulate (pad rows guarded)
#pragma unroll
  for (int mf = 0; mf < 4; ++mf) {
#pragma unroll
    for (int rr = 0; rr < 4; ++rr) {
      const int row = mt * 128 + wm + mf * 16 + lquad * 4 + rr;
      const int tk = etk[ebase + row];
      const int tok = tk >> 2;
      if (tok < T_TOK)
        atomicAdd(out + (size_t)tok * HDIM + n0 + wh + lcol, acc[mf][rr]);
    }
  }
}

// ---------------- launch ----------------

extern "C" void kernel_launch(void* const* d_in, const int* in_sizes, int n_in,
                              void* d_out, int out_size, void* d_ws, size_t ws_size,
                              hipStream_t stream) {
  const float* hid_f  = (const float*)d_in[0];
  const int*   idx    = (const int*)d_in[1];
  const float* tw     = (const float*)d_in[2];
  const float* gup_f  = (const float*)d_in[3];
  const float* down_f = (const float*)d_in[4];
  float* out = (float*)d_out;

  uint8_t* ws = (uint8_t*)d_ws;
  size_t off = 0;
  bf16* hid_b = (bf16*)(ws + off);   off += (size_t)(T_TOK + 1) * HDIM * 2;
  int*  etk   = (int*)(ws + off);    off += (size_t)NEXP * CAP * 4;
  float* ewt  = (float*)(ws + off);  off += (size_t)NEXP * CAP * 4;
  int* cntpad = (int*)(ws + off);    off += 256;
  bf16* hsc   = (bf16*)(ws + off);   // 16 MB

  prep_kernel<<<dim3(CVT_BLOCKS + NEXP), dim3(256), 0, stream>>>(
      hid_f, hid_b, idx, tw, etk, ewt, cntpad, out);
  gemm1_kernel<<<dim3(IDIM / 32, MAXTILES), dim3(256), 0, stream>>>(
      hid_b, gup_f, etk, ewt, cntpad, hsc);
  gemm2_kernel<<<dim3(HDIM / 32, MAXTILES), dim3(256), 0, stream>>>(
      hsc, down_f, etk, cntpad, out);
}

// Round 8
// 209.162 us; speedup vs baseline: 1.3064x; 1.3064x over previous
//
#include <hip/hip_runtime.h>
#include <hip/hip_bf16.h>
#include <cstdint>
#include <cstddef>

// Problem constants: T=1024, H=1024, I=512, E=16, K=4
#define T_TOK 1024
#define HDIM  1024
#define IDIM  512
#define NEXP  16
#define TOPK  4
#define CAP   1024   // per-expert entry capacity
#define MAXTILES 80  // max sum of ceil(cnt_e/64) = 4096/64 + 16 = 80

typedef __bf16 bf16;
typedef __attribute__((ext_vector_type(8))) __bf16 bf16x8;
typedef __attribute__((ext_vector_type(4))) __bf16 bf16x4;
typedef __attribute__((ext_vector_type(4))) float f32x4;

#define BAR() __builtin_amdgcn_s_barrier()
#define SB()  __builtin_amdgcn_sched_barrier(0)

__device__ __forceinline__ void lds_load16(void* lds_dst, const void* g_src) {
  __builtin_amdgcn_global_load_lds(
      (__attribute__((address_space(1))) unsigned int*)(void*)(g_src),
      (__attribute__((address_space(3))) unsigned int*)(lds_dst),
      16, 0, 0);
}

__device__ __forceinline__ bf16x4 cvt4(float4 a) {
  bf16x4 o;
  o[0] = (bf16)a.x; o[1] = (bf16)a.y; o[2] = (bf16)a.z; o[3] = (bf16)a.w;
  return o;
}

// flat tile index -> (expert, m-tile) scanning cntpad (M-tile = 64).
__device__ __forceinline__ bool tile_lookup(const int* cntpad, int idx,
                                            int& e_out, int& mt_out) {
  int rem = idx;
  for (int e = 0; e < NEXP; ++e) {
    int nt = cntpad[e] >> 6;
    if (rem < nt) { e_out = e; mt_out = rem; return true; }
    rem -= nt;
  }
  return false;
}

// ---------------- fused prep: cvt hid->bf16, zero out, routing ----------------

#define CVT_BLOCKS (T_TOK * HDIM / 4 / 256)   // 1024

__global__ void prep_kernel(const float* __restrict__ hid_f, bf16* __restrict__ hid_b,
                            const int* __restrict__ idx, const float* __restrict__ w,
                            int* __restrict__ etk, float* __restrict__ ew,
                            int* __restrict__ cntpad, float* __restrict__ out) {
  __shared__ int cnt;
  const int b = blockIdx.x;
  const int tid = threadIdx.x;
  if (b < CVT_BLOCKS) {
    int i = b * 256 + tid;
    float4 v = ((const float4*)hid_f)[i];
    ((bf16x4*)hid_b)[i] = cvt4(v);
    ((float4*)out)[i] = make_float4(0.f, 0.f, 0.f, 0.f);
    if (b == 0)  // zero pad row T
      ((bf16x4*)(hid_b + (size_t)T_TOK * HDIM))[tid] = cvt4(make_float4(0.f, 0.f, 0.f, 0.f));
    return;
  }
  const int e = b - CVT_BLOCKS;
  if (tid == 0) cnt = 0;
  __syncthreads();
  for (int j = tid; j < T_TOK * TOPK; j += blockDim.x) {
    if (idx[j] == e) {
      int slot = atomicAdd(&cnt, 1);
      if (slot < CAP) { etk[e * CAP + slot] = j; ew[e * CAP + slot] = w[j]; }
    }
  }
  __syncthreads();
  int c = cnt < CAP ? cnt : CAP;
  int p = (c + 63) & ~63;              // pad to M-tile (64)
  for (int j = c + tid; j < p; j += blockDim.x) {
    etk[e * CAP + j] = (T_TOK << 2);   // points at zeroed row T
    ew[e * CAP + j] = 0.f;
  }
  if (tid == 0) cntpad[e] = p;
}

// ---------------- GEMM1: hsc[entry, i] = silu(g)*u*wgt ----------------
// v8: coalesced-B + no-drain pipeline, ZERO manual waitcnt.
//  - A: shared As[2] via global_load_lds; ONE raw s_barrier per K-step.
//  - B: PER-WAVE PRIVATE LDS (same wave writes & reads -> DS wave-order, no
//    barrier/no WAR window). Coalesced loads: 16 rows x 64B per instr.
//  - Safety: iter k issues A(k+1) BEFORE B(k+1); iter k+1's private ds_write
//    makes the compiler emit an exact vmcnt wait on B(k+1); in-order VMEM
//    retirement => A(k+1) landed too => barrier needs no drain.
// Tile M=64 x 32 i-ch (G+U); waves 2m x 2i; BK=64, 16 steps, 8 MFMA/wave/step.
// LDS 32 KB -> 4 blk/CU. Grid (16, MAXTILES) -> ~1088 active blocks.

__global__ __launch_bounds__(256, 4) void gemm1_kernel(
    const bf16* __restrict__ hid,    // [(T+1),H] bf16, row T zeroed
    const float* __restrict__ gup,   // [E,2I,H] fp32
    const int* __restrict__ etk, const float* __restrict__ ew,
    const int* __restrict__ cntpad,
    bf16* __restrict__ hsc) {        // [E*CAP, I] bf16
  __shared__ __align__(16) bf16 As[2][64 * 64];   // 16 KB
  __shared__ __align__(16) bf16 Bp[4][32 * 64];   // 16 KB, per-wave private
  int e, mt;
  if (!tile_lookup(cntpad, blockIdx.y, e, mt)) return;
  const int n0 = blockIdx.x * 32;
  const int ebase = e * CAP;
  const int tid = threadIdx.x, lane = tid & 63, wid = tid >> 6;
  const int wm = (wid >> 1) * 32, wi = (wid & 1) * 16;
  const int lcol = lane & 15, lquad = lane >> 4;
  const int l7 = lcol & 7;
  const int srow = tid >> 3;                 // 0..31
  const int swz = ((tid & 7) ^ (srow & 7)) * 8;
  const bf16* gA[2];
#pragma unroll
  for (int q = 0; q < 2; ++q)
    gA[q] = hid + (size_t)(etk[ebase + mt * 64 + srow + 32 * q] >> 2) * HDIM + swz;
  // B loader: 4 lanes/row x float4 (64B chunks); 16 rows/instr
  const int br = lane >> 2, bc = (lane & 3) * 4;
  const float* gG = gup + (size_t)e * (2 * IDIM) * HDIM
                  + (size_t)(n0 + wi + br) * HDIM + bc;
  const float* gU = gG + (size_t)IDIM * HDIM;
  bf16* myB = &Bp[wid][0];
  int wG[4], wU[4];
#pragma unroll
  for (int j = 0; j < 4; ++j) {
    int cf = bc + j * 16;
    int s = (((cf >> 3) ^ (br & 7)) * 8) + (cf & 7);
    wG[j] = br * 64 + s;
    wU[j] = (16 + br) * 64 + s;
  }

  f32x4 aG[2], aU[2];
#pragma unroll
  for (int mf = 0; mf < 2; ++mf) {
    aG[mf] = f32x4{0.f, 0.f, 0.f, 0.f};
    aU[mf] = f32x4{0.f, 0.f, 0.f, 0.f};
  }
  float4 gA_[2][4], uA_[2][4];   // two rotating B register sets (static names)

  // prologue: A(0) first (older), then B(0) -> set0
#pragma unroll
  for (int q = 0; q < 2; ++q)
    lds_load16(&As[0][tid * 8 + q * 2048], gA[q]);
#pragma unroll
  for (int j = 0; j < 4; ++j) {
    gA_[0][j] = *(const float4*)(gG + j * 16);
    uA_[0][j] = *(const float4*)(gU + j * 16);
  }

#pragma unroll
  for (int k = 0; k < 16; ++k) {
    const int cur = k & 1, nxt = cur ^ 1;
    const int cs = k & 1;        // B set holding B(k), ns = other
    const int ns = cs ^ 1;
    // 1. stage B(k) -> private LDS (compiler: exact vmcnt wait on B(k);
    //    in-order retirement => A(k) landed too)
#pragma unroll
    for (int j = 0; j < 4; ++j) {
      *(bf16x4*)&myB[wG[j]] = cvt4(gA_[cs][j]);
      *(bf16x4*)&myB[wU[j]] = cvt4(uA_[cs][j]);
    }
    SB();
    BAR();   // all waves: A(k) staged & visible; prev compute done -> As[nxt] free
    SB();
    // 2. issue A(k+1) (older) then B(k+1) (younger)
    if (k + 1 < 16) {
#pragma unroll
      for (int q = 0; q < 2; ++q)
        lds_load16(&As[nxt][tid * 8 + q * 2048], gA[q] + (k + 1) * 64);
#pragma unroll
      for (int j = 0; j < 4; ++j) {
        gA_[ns][j] = *(const float4*)(gG + (k + 1) * 64 + j * 16);
        uA_[ns][j] = *(const float4*)(gU + (k + 1) * 64 + j * 16);
      }
    }
    // 3. compute on As[cur] x myB (B(k))
    __builtin_amdgcn_s_setprio(1);
#pragma unroll
    for (int ks = 0; ks < 2; ++ks) {
      const int sw = ((ks * 4 + lquad) ^ l7) * 8;
      bf16x8 bg = *(const bf16x8*)&myB[lcol * 64 + sw];
      bf16x8 bu = *(const bf16x8*)&myB[(16 + lcol) * 64 + sw];
#pragma unroll
      for (int mf = 0; mf < 2; ++mf) {
        const int row = wm + mf * 16 + lcol;
        bf16x8 af = *(const bf16x8*)&As[cur][row * 64 + ((ks * 4 + lquad) ^ (row & 7)) * 8];
        aG[mf] = __builtin_amdgcn_mfma_f32_16x16x32_bf16(af, bg, aG[mf], 0, 0, 0);
        aU[mf] = __builtin_amdgcn_mfma_f32_16x16x32_bf16(af, bu, aU[mf], 0, 0, 0);
      }
    }
    __builtin_amdgcn_s_setprio(0);
  }

  // epilogue: C/D col=lane&15, row=lquad*4+rr
#pragma unroll
  for (int mf = 0; mf < 2; ++mf) {
#pragma unroll
    for (int rr = 0; rr < 4; ++rr) {
      const int erow = mt * 64 + wm + mf * 16 + lquad * 4 + rr;
      const float wgt = ew[ebase + erow];
      float g = aG[mf][rr], u = aU[mf][rr];
      float s = g / (1.f + __expf(-g));
      hsc[(size_t)(ebase + erow) * IDIM + n0 + wi + lcol] = (bf16)(s * u * wgt);
    }
  }
}

// ---------------- GEMM2: out[tok,h] += hsc[entry,:] . down[e,h,:] ----------------
// Same v8 pipeline. Tile M=64 x 64 h-ch; waves 2m x 2h (wave 32m x 32h);
// BK=64, 8 steps, 8 MFMA/wave/step. atomicAdd epilogue into pre-zeroed out.
// LDS 32 KB. Grid (16, MAXTILES).

__global__ __launch_bounds__(256, 4) void gemm2_kernel(
    const bf16* __restrict__ hsc,    // [E*CAP, I] bf16
    const float* __restrict__ down,  // [E,H,I] fp32
    const int* __restrict__ etk, const int* __restrict__ cntpad,
    float* __restrict__ out) {       // [T,H] fp32, pre-zeroed
  __shared__ __align__(16) bf16 As[2][64 * 64];   // 16 KB
  __shared__ __align__(16) bf16 Bp[4][32 * 64];   // 16 KB per-wave private
  int e, mt;
  if (!tile_lookup(cntpad, blockIdx.y, e, mt)) return;
  const int n0 = blockIdx.x * 64;
  const int ebase = e * CAP;
  const int tid = threadIdx.x, lane = tid & 63, wid = tid >> 6;
  const int wm = (wid >> 1) * 32, wh = (wid & 1) * 32;
  const int lcol = lane & 15, lquad = lane >> 4;
  const int l7 = lcol & 7;
  const int srow = tid >> 3;
  const int swz = ((tid & 7) ^ (srow & 7)) * 8;
  const bf16* gA[2];
#pragma unroll
  for (int q = 0; q < 2; ++q)
    gA[q] = hsc + (size_t)(ebase + mt * 64 + srow + 32 * q) * IDIM + swz;
  // B loader: rows p*16+br (p=0,1), 64B chunks
  const int br = lane >> 2, bc = (lane & 3) * 4;
  const float* gB = down + (size_t)e * HDIM * IDIM
                  + (size_t)(n0 + wh + br) * IDIM + bc;   // +p*16 rows via ptr
  const float* gB1 = gB + (size_t)16 * IDIM;
  bf16* myB = &Bp[wid][0];
  int wB[2][4];
#pragma unroll
  for (int p = 0; p < 2; ++p)
#pragma unroll
    for (int j = 0; j < 4; ++j) {
      int cf = bc + j * 16;
      int s = (((cf >> 3) ^ (br & 7)) * 8) + (cf & 7);
      wB[p][j] = (p * 16 + br) * 64 + s;
    }

  f32x4 acc[2][2];
#pragma unroll
  for (int mf = 0; mf < 2; ++mf) {
    acc[mf][0] = f32x4{0.f, 0.f, 0.f, 0.f};
    acc[mf][1] = f32x4{0.f, 0.f, 0.f, 0.f};
  }
  float4 b0_[2][4], b1_[2][4];

#pragma unroll
  for (int q = 0; q < 2; ++q)
    lds_load16(&As[0][tid * 8 + q * 2048], gA[q]);
#pragma unroll
  for (int j = 0; j < 4; ++j) {
    b0_[0][j] = *(const float4*)(gB + j * 16);
    b1_[0][j] = *(const float4*)(gB1 + j * 16);
  }

#pragma unroll
  for (int k = 0; k < 8; ++k) {   // IDIM/64
    const int cur = k & 1, nxt = cur ^ 1;
    const int cs = k & 1, ns = cs ^ 1;
#pragma unroll
    for (int j = 0; j < 4; ++j) {
      *(bf16x4*)&myB[wB[0][j]] = cvt4(b0_[cs][j]);
      *(bf16x4*)&myB[wB[1][j]] = cvt4(b1_[cs][j]);
    }
    SB();
    BAR();
    SB();
    if (k + 1 < 8) {
#pragma unroll
      for (int q = 0; q < 2; ++q)
        lds_load16(&As[nxt][tid * 8 + q * 2048], gA[q] + (k + 1) * 64);
#pragma unroll
      for (int j = 0; j < 4; ++j) {
        b0_[ns][j] = *(const float4*)(gB + (k + 1) * 64 + j * 16);
        b1_[ns][j] = *(const float4*)(gB1 + (k + 1) * 64 + j * 16);
      }
    }
    __builtin_amdgcn_s_setprio(1);
#pragma unroll
    for (int ks = 0; ks < 2; ++ks) {
      const int sw = ((ks * 4 + lquad) ^ l7) * 8;
      bf16x8 bf0 = *(const bf16x8*)&myB[lcol * 64 + sw];
      bf16x8 bf1 = *(const bf16x8*)&myB[(16 + lcol) * 64 + sw];
#pragma unroll
      for (int mf = 0; mf < 2; ++mf) {
        const int row = wm + mf * 16 + lcol;
        bf16x8 af = *(const bf16x8*)&As[cur][row * 64 + ((ks * 4 + lquad) ^ (row & 7)) * 8];
        acc[mf][0] = __builtin_amdgcn_mfma_f32_16x16x32_bf16(af, bf0, acc[mf][0], 0, 0, 0);
        acc[mf][1] = __builtin_amdgcn_mfma_f32_16x16x32_bf16(af, bf1, acc[mf][1], 0, 0, 0);
      }
    }
    __builtin_amdgcn_s_setprio(0);
  }

  // epilogue: atomic scatter-accumulate (pad rows guarded)
#pragma unroll
  for (int mf = 0; mf < 2; ++mf) {
#pragma unroll
    for (int rr = 0; rr < 4; ++rr) {
      const int row = mt * 64 + wm + mf * 16 + lquad * 4 + rr;
      const int tk = etk[ebase + row];
      const int tok = tk >> 2;
      if (tok < T_TOK) {
        float* orow = out + (size_t)tok * HDIM + n0 + wh + lcol;
        atomicAdd(orow, acc[mf][0][rr]);
        atomicAdd(orow + 16, acc[mf][1][rr]);
      }
    }
  }
}

// ---------------- launch ----------------

extern "C" void kernel_launch(void* const* d_in, const int* in_sizes, int n_in,
                              void* d_out, int out_size, void* d_ws, size_t ws_size,
                              hipStream_t stream) {
  const float* hid_f  = (const float*)d_in[0];
  const int*   idx    = (const int*)d_in[1];
  const float* tw     = (const float*)d_in[2];
  const float* gup_f  = (const float*)d_in[3];
  const float* down_f = (const float*)d_in[4];
  float* out = (float*)d_out;

  uint8_t* ws = (uint8_t*)d_ws;
  size_t off = 0;
  bf16* hid_b = (bf16*)(ws + off);   off += (size_t)(T_TOK + 1) * HDIM * 2;
  int*  etk   = (int*)(ws + off);    off += (size_t)NEXP * CAP * 4;
  float* ewt  = (float*)(ws + off);  off += (size_t)NEXP * CAP * 4;
  int* cntpad = (int*)(ws + off);    off += 256;
  bf16* hsc   = (bf16*)(ws + off);   // 16 MB

  prep_kernel<<<dim3(CVT_BLOCKS + NEXP), dim3(256), 0, stream>>>(
      hid_f, hid_b, idx, tw, etk, ewt, cntpad, out);
  gemm1_kernel<<<dim3(IDIM / 32, MAXTILES), dim3(256), 0, stream>>>(
      hid_b, gup_f, etk, ewt, cntpad, hsc);
  gemm2_kernel<<<dim3(HDIM / 64, MAXTILES), dim3(256), 0, stream>>>(
      hsc, down_f, etk, cntpad, out);
}

// Round 9
// 169.073 us; speedup vs baseline: 1.6161x; 1.2371x over previous
//
#include <hip/hip_runtime.h>
#include <hip/hip_bf16.h>
#include <cstdint>
#include <cstddef>

// Problem constants: T=1024, H=1024, I=512, E=16, K=4
#define T_TOK 1024
#define HDIM  1024
#define IDIM  512
#define NEXP  16
#define TOPK  4
#define CAP   1024   // per-expert entry capacity

typedef __bf16 bf16;
typedef __attribute__((ext_vector_type(8))) __bf16 bf16x8;
typedef __attribute__((ext_vector_type(4))) __bf16 bf16x4;
typedef __attribute__((ext_vector_type(4))) float f32x4;

#define BAR() __builtin_amdgcn_s_barrier()
#define SB()  __builtin_amdgcn_sched_barrier(0)
// ds-write visibility fence before s_barrier (waits DS only, NOT VMEM --
// the whole point: prefetch VMEM stays in flight across the barrier)
#define LGKM0() asm volatile("s_waitcnt lgkmcnt(0)" ::: "memory")

__device__ __forceinline__ void lds_load16(void* lds_dst, const void* g_src) {
  __builtin_amdgcn_global_load_lds(
      (__attribute__((address_space(1))) unsigned int*)(void*)(g_src),
      (__attribute__((address_space(3))) unsigned int*)(lds_dst),
      16, 0, 0);
}

__device__ __forceinline__ bf16x4 cvt4(float4 a) {
  bf16x4 o;
  o[0] = (bf16)a.x; o[1] = (bf16)a.y; o[2] = (bf16)a.z; o[3] = (bf16)a.w;
  return o;
}

// ---------------- fused prep: cvt hid->bf16 (+zero row T) and routing ----------------

#define CVT_BLOCKS (T_TOK * HDIM / 4 / 256)   // 1024

__global__ void prep_kernel(const float* __restrict__ hid_f, bf16* __restrict__ hid_b,
                            const int* __restrict__ idx, const float* __restrict__ w,
                            int* __restrict__ etk, float* __restrict__ ew,
                            int* __restrict__ cntpad) {
  __shared__ int cnt;
  const int b = blockIdx.x;
  const int tid = threadIdx.x;
  if (b < CVT_BLOCKS) {
    int i = b * 256 + tid;
    float4 v = ((const float4*)hid_f)[i];
    ((bf16x4*)hid_b)[i] = cvt4(v);
    if (b == 0)  // zero pad row T
      ((bf16x4*)(hid_b + (size_t)T_TOK * HDIM))[tid] = cvt4(make_float4(0.f, 0.f, 0.f, 0.f));
    return;
  }
  const int e = b - CVT_BLOCKS;
  if (tid == 0) cnt = 0;
  __syncthreads();
  for (int j = tid; j < T_TOK * TOPK; j += blockDim.x) {
    if (idx[j] == e) {
      int slot = atomicAdd(&cnt, 1);
      if (slot < CAP) { etk[e * CAP + slot] = j; ew[e * CAP + slot] = w[j]; }
    }
  }
  __syncthreads();
  int c = cnt < CAP ? cnt : CAP;
  int p = (c + 127) & ~127;            // pad to M-tile (128)
  for (int j = c + tid; j < p; j += blockDim.x) {
    etk[e * CAP + j] = (T_TOK << 2);   // points at zeroed row T; kslot 0 -> slab pad row T
    ew[e * CAP + j] = 0.f;
  }
  if (tid == 0) cntpad[e] = p;
}

// ---------------- GEMM1: hsc[entry, i] = silu(g)*u*wgt ----------------
// v9 = R1 geometry + v8 no-drain barrier discipline.
//  - Tile M=128 x 32 i-ch (G+U), BK=64, 16 steps, waves 2m x 2i, 16 MFMA/wave/step.
//  - As[2] via global_load_lds, Bs[2] via reg->ds_write (R1 zero-conflict layouts).
//  - Per K-step: ds_write B(k) [compiler emits exact vmcnt wait on B(k); older
//    A(k) global_load_lds retired in-order] -> lgkmcnt(0) [DS only!] -> s_barrier
//    -> issue A(k+1) then B(k+1) [stay in flight across next barrier] -> compute.
//    No vmcnt(0) drain anywhere: prefetch gets a full iteration of cover.
//  - Rotating B reg sets are static (bvA/bvB, literal cur) per rule #20.
// Grid (16,16,3)=768 = 3 blocks/CU exactly; LDS 48 KB.

__global__ __launch_bounds__(256, 3) void gemm1_kernel(
    const bf16* __restrict__ hid,    // [(T+1),H] bf16, row T zeroed
    const float* __restrict__ gup,   // [E,2I,H] fp32
    const int* __restrict__ etk, const float* __restrict__ ew,
    const int* __restrict__ cntpad,
    bf16* __restrict__ hsc) {        // [E*CAP, I] bf16
  __shared__ __align__(16) bf16 As[2][128 * 64];  // 32 KB
  __shared__ __align__(16) bf16 Bs[2][64 * 64];   // 16 KB (32 G rows + 32 U rows)
  const int e = blockIdx.y, z = blockIdx.z;
  const int ntiles = cntpad[e] >> 7;
  const int n0 = blockIdx.x * 32;
  const int ebase = e * CAP;
  const int tid = threadIdx.x, lane = tid & 63, wid = tid >> 6;
  const int wm = (wid >> 1) * 64, wi = (wid & 1) * 16;
  const int lcol = lane & 15, lquad = lane >> 4;
  const int l7 = lcol & 7;
  const int srow = tid >> 3;
  const int swz = ((tid & 7) ^ (srow & 7)) * 8;
  const int r = tid >> 2;
  const int c0 = (tid & 3) * 4;
  const int grow = (r < 32) ? (n0 + r) : (IDIM + n0 + (r - 32));
  const float* gB = gup + (size_t)e * (2 * IDIM) * HDIM + (size_t)grow * HDIM + c0;
  int wb[4];
#pragma unroll
  for (int j = 0; j < 4; ++j) {
    int c = c0 + 16 * j;
    wb[j] = (((c >> 3) ^ (r & 7)) * 8) + (c & 7);
  }
  const int bst = r * 64;

  for (int mt = z; mt < ntiles; mt += 3) {
    const int mrow = ebase + mt * 128;
    const bf16* gA[4];
#pragma unroll
    for (int q = 0; q < 4; ++q)
      gA[q] = hid + (size_t)(etk[mrow + srow + 32 * q] >> 2) * HDIM + swz;
    f32x4 aG[4], aU[4];
#pragma unroll
    for (int mf = 0; mf < 4; ++mf) {
      aG[mf] = f32x4{0.f, 0.f, 0.f, 0.f};
      aU[mf] = f32x4{0.f, 0.f, 0.f, 0.f};
    }
    float4 bvA[4], bvB[4];

    // prologue: issue A(0) (older) then B(0) (younger) -> set A
#pragma unroll
    for (int q = 0; q < 4; ++q)
      lds_load16(&As[0][tid * 8 + q * 2048], gA[q]);
    SB();
#pragma unroll
    for (int j = 0; j < 4; ++j) bvA[j] = *(const float4*)(gB + 16 * j);
    SB();

    auto STEP = [&](int k, int cur, float4 (&bcur)[4], float4 (&bnxt)[4]) {
      const int nxt = cur ^ 1;
      // stage B(k): forces exact vmcnt wait on bcur; A(k) older => landed
#pragma unroll
      for (int j = 0; j < 4; ++j)
        *(bf16x4*)&Bs[cur][bst + wb[j]] = cvt4(bcur[j]);
      LGKM0();   // DS visibility only; VMEM prefetch stays in flight
      SB();
      BAR();
      SB();
      if (k < 15) {  // issue k+1: A first (older), then B
#pragma unroll
        for (int q = 0; q < 4; ++q)
          lds_load16(&As[nxt][tid * 8 + q * 2048], gA[q] + (k + 1) * 64);
        SB();
#pragma unroll
        for (int j = 0; j < 4; ++j)
          bnxt[j] = *(const float4*)(gB + (k + 1) * 64 + 16 * j);
        SB();
      }
      // compute on As[cur] x Bs[cur]
#pragma unroll
      for (int ks = 0; ks < 2; ++ks) {
        const int sw = ((ks * 4 + lquad) ^ l7) * 8;
        bf16x8 bg = *(const bf16x8*)&Bs[cur][(wi + lcol) * 64 + sw];
        bf16x8 bu = *(const bf16x8*)&Bs[cur][(32 + wi + lcol) * 64 + sw];
#pragma unroll
        for (int mf = 0; mf < 4; ++mf) {
          bf16x8 af = *(const bf16x8*)&As[cur][(wm + mf * 16 + lcol) * 64 + sw];
          aG[mf] = __builtin_amdgcn_mfma_f32_16x16x32_bf16(af, bg, aG[mf], 0, 0, 0);
          aU[mf] = __builtin_amdgcn_mfma_f32_16x16x32_bf16(af, bu, aU[mf], 0, 0, 0);
        }
      }
    };
#pragma unroll
    for (int kk = 0; kk < 8; ++kk) {
      STEP(2 * kk,     0, bvA, bvB);
      STEP(2 * kk + 1, 1, bvB, bvA);
    }
    // epilogue: C/D col=lane&15, row=lquad*4+rr
#pragma unroll
    for (int mf = 0; mf < 4; ++mf) {
#pragma unroll
      for (int rr = 0; rr < 4; ++rr) {
        const int erow = mt * 128 + wm + mf * 16 + lquad * 4 + rr;
        const float wgt = ew[ebase + erow];
        float g = aG[mf][rr], u = aU[mf][rr];
        float s = g / (1.f + __expf(-g));
        hsc[(size_t)(ebase + erow) * IDIM + n0 + wi + lcol] = (bf16)(s * u * wgt);
      }
    }
  }
}

// ---------------- GEMM2: slab[k][tok,h] = hsc[entry,:] . down[e,h,:] ----------------
// Same v9 discipline, 8 K-steps. Tile M=128 x 64 h-ch, waves 2m x 2h,
// 16 MFMA/wave/step. Slabs + reduce epilogue (R1-proven faster than atomics).

__global__ __launch_bounds__(256, 3) void gemm2_kernel(
    const bf16* __restrict__ hsc,    // [E*CAP, I] bf16
    const float* __restrict__ down,  // [E,H,I] fp32
    const int* __restrict__ etk, const int* __restrict__ cntpad,
    float* __restrict__ slabs) {     // [4][(T+1)][H] fp32
  __shared__ __align__(16) bf16 As[2][128 * 64];  // 32 KB
  __shared__ __align__(16) bf16 Bs[2][64 * 64];   // 16 KB
  const int e = blockIdx.y, z = blockIdx.z;
  const int ntiles = cntpad[e] >> 7;
  const int n0 = blockIdx.x * 64;
  const int ebase = e * CAP;
  const int tid = threadIdx.x, lane = tid & 63, wid = tid >> 6;
  const int wm = (wid >> 1) * 64, wh = (wid & 1) * 32;
  const int lcol = lane & 15, lquad = lane >> 4;
  const int l7 = lcol & 7;
  const int srow = tid >> 3;
  const int swz = ((tid & 7) ^ (srow & 7)) * 8;
  const int r = tid >> 2;
  const int c0 = (tid & 3) * 4;
  const float* gB = down + (size_t)e * HDIM * IDIM + (size_t)(n0 + r) * IDIM + c0;
  int wb[4];
#pragma unroll
  for (int j = 0; j < 4; ++j) {
    int c = c0 + 16 * j;
    wb[j] = (((c >> 3) ^ (r & 7)) * 8) + (c & 7);
  }
  const int bst = r * 64;

  for (int mt = z; mt < ntiles; mt += 3) {
    const size_t rbase = (size_t)(ebase + mt * 128);
    const bf16* gA[4];
#pragma unroll
    for (int q = 0; q < 4; ++q)
      gA[q] = hsc + (rbase + srow + 32 * q) * IDIM + swz;
    f32x4 acc[4][2];
#pragma unroll
    for (int mf = 0; mf < 4; ++mf) {
      acc[mf][0] = f32x4{0.f, 0.f, 0.f, 0.f};
      acc[mf][1] = f32x4{0.f, 0.f, 0.f, 0.f};
    }
    float4 bvA[4], bvB[4];
#pragma unroll
    for (int q = 0; q < 4; ++q)
      lds_load16(&As[0][tid * 8 + q * 2048], gA[q]);
    SB();
#pragma unroll
    for (int j = 0; j < 4; ++j) bvA[j] = *(const float4*)(gB + 16 * j);
    SB();

    auto STEP = [&](int k, int cur, float4 (&bcur)[4], float4 (&bnxt)[4]) {
      const int nxt = cur ^ 1;
#pragma unroll
      for (int j = 0; j < 4; ++j)
        *(bf16x4*)&Bs[cur][bst + wb[j]] = cvt4(bcur[j]);
      LGKM0();
      SB();
      BAR();
      SB();
      if (k < 7) {
#pragma unroll
        for (int q = 0; q < 4; ++q)
          lds_load16(&As[nxt][tid * 8 + q * 2048], gA[q] + (k + 1) * 64);
        SB();
#pragma unroll
        for (int j = 0; j < 4; ++j)
          bnxt[j] = *(const float4*)(gB + (k + 1) * 64 + 16 * j);
        SB();
      }
#pragma unroll
      for (int ks = 0; ks < 2; ++ks) {
        const int sw = ((ks * 4 + lquad) ^ l7) * 8;
        bf16x8 b0 = *(const bf16x8*)&Bs[cur][(wh + lcol) * 64 + sw];
        bf16x8 b1 = *(const bf16x8*)&Bs[cur][(wh + 16 + lcol) * 64 + sw];
#pragma unroll
        for (int mf = 0; mf < 4; ++mf) {
          bf16x8 af = *(const bf16x8*)&As[cur][(wm + mf * 16 + lcol) * 64 + sw];
          acc[mf][0] = __builtin_amdgcn_mfma_f32_16x16x32_bf16(af, b0, acc[mf][0], 0, 0, 0);
          acc[mf][1] = __builtin_amdgcn_mfma_f32_16x16x32_bf16(af, b1, acc[mf][1], 0, 0, 0);
        }
      }
    };
#pragma unroll
    for (int kk = 0; kk < 4; ++kk) {   // IDIM/64 = 8 steps
      STEP(2 * kk,     0, bvA, bvB);
      STEP(2 * kk + 1, 1, bvB, bvA);
    }
    // epilogue: plain scatter stores (each (t,k) slab row written once per n-slice)
#pragma unroll
    for (int mf = 0; mf < 4; ++mf) {
#pragma unroll
      for (int rr = 0; rr < 4; ++rr) {
        const int tk = etk[ebase + mt * 128 + wm + mf * 16 + lquad * 4 + rr];
        const int tok = tk >> 2, kslot = tk & 3;
        float* orow = slabs + ((size_t)kslot * (T_TOK + 1) + tok) * HDIM + n0 + wh + lcol;
        orow[0] = acc[mf][0][rr];
        orow[16] = acc[mf][1][rr];
      }
    }
  }
}

// ---------------- reduce: out = sum of 4 slabs ----------------

__global__ void reduce_kernel(const float* __restrict__ slabs, float* __restrict__ out) {
  const size_t stride = (size_t)(T_TOK + 1) * HDIM;
  int i = blockIdx.x * blockDim.x + threadIdx.x;
  float4 a = ((const float4*)slabs)[i];
  float4 b = ((const float4*)(slabs + stride))[i];
  float4 c = ((const float4*)(slabs + 2 * stride))[i];
  float4 d = ((const float4*)(slabs + 3 * stride))[i];
  float4 o;
  o.x = a.x + b.x + c.x + d.x;
  o.y = a.y + b.y + c.y + d.y;
  o.z = a.z + b.z + c.z + d.z;
  o.w = a.w + b.w + c.w + d.w;
  ((float4*)out)[i] = o;
}

// ---------------- launch ----------------

extern "C" void kernel_launch(void* const* d_in, const int* in_sizes, int n_in,
                              void* d_out, int out_size, void* d_ws, size_t ws_size,
                              hipStream_t stream) {
  const float* hid_f  = (const float*)d_in[0];
  const int*   idx    = (const int*)d_in[1];
  const float* tw     = (const float*)d_in[2];
  const float* gup_f  = (const float*)d_in[3];
  const float* down_f = (const float*)d_in[4];
  float* out = (float*)d_out;

  uint8_t* ws = (uint8_t*)d_ws;
  size_t off = 0;
  bf16* hid_b = (bf16*)(ws + off);   off += (size_t)(T_TOK + 1) * HDIM * 2;
  int*  etk   = (int*)(ws + off);    off += (size_t)NEXP * CAP * 4;
  float* ewt  = (float*)(ws + off);  off += (size_t)NEXP * CAP * 4;
  int* cntpad = (int*)(ws + off);    off += 256;
  bf16* hsc   = (bf16*)(ws + off);   off += (size_t)NEXP * CAP * IDIM * 2;
  float* slabs = (float*)(ws + off); // 4*(T+1)*H*4 ≈ 16.8 MB

  prep_kernel<<<dim3(CVT_BLOCKS + NEXP), dim3(256), 0, stream>>>(
      hid_f, hid_b, idx, tw, etk, ewt, cntpad);
  gemm1_kernel<<<dim3(IDIM / 32, NEXP, 3), dim3(256), 0, stream>>>(
      hid_b, gup_f, etk, ewt, cntpad, hsc);
  gemm2_kernel<<<dim3(HDIM / 64, NEXP, 3), dim3(256), 0, stream>>>(
      hsc, down_f, etk, cntpad, slabs);
  reduce_kernel<<<dim3(T_TOK * HDIM / 4 / 256), dim3(256), 0, stream>>>(slabs, out);
}